// Round 4
// baseline (213.274 us; speedup 1.0000x reference)
//
#include <hip/hip_runtime.h>

// Problem constants (from reference)
constexpr int B     = 16384;
constexpr int NNEG  = 10;
constexpr int D     = 8;
constexpr int E     = 64;               // 64 floats = 256B per table row
constexpr int ROWS  = B * (1 + NNEG);   // 180224; flat row id == output index
constexpr int RPW   = 8;                // rows per wave: 2 sets x 4 rows

// pair_sum = sum_{i<j} e_i.e_j = 0.5*(||sum_d e_d||^2 - sum_d ||e_d||^2).
//
// Packing: lane l -> row-group g=l>>4, quad t=l&15 owns dims [4t,4t+4).
// One global_load_dwordx4 per (set,d) gathers FOUR random rows as contiguous
// 256B segments (16 lanes x 16B each) = 16 fully-consumed cache lines per
// instruction. 16 such instructions in flight = 16KB/wave over 16 vmcnt slots
// (4x fewer VMEM instructions per byte than the lane-per-dim layout).
__global__ __launch_bounds__(256) void APE_61555471286335_kernel(
    const int*   __restrict__ pos_x,   // [B, D]
    const int*   __restrict__ neg_x,   // [B, NNEG, D]
    const float* __restrict__ emb,     // [N_ENT, E]
    const float* __restrict__ pair_w,  // [N_PAIRS]
    const float* __restrict__ c,       // [1]
    float*       __restrict__ out)     // [ROWS]
{
    const int tid  = blockIdx.x * blockDim.x + threadIdx.x;
    const int wave = tid >> 6;
    const int lane = threadIdx.x & 63;
    const int g    = lane >> 4;        // row within set (0..3)
    const int t    = lane & 15;        // quad owner: dims [4t, 4t+4)
    const int row0 = wave * RPW;       // ROWS % 32 == 0, exact grid
    const int rowA = row0 + g;
    const int rowB = row0 + 4 + g;

    // Per-lane (uniform within each 16-lane group) index fetch, 2x int4 each.
    const int* idxA = (rowA < B) ? (pos_x + (size_t)rowA * D)
                                 : (neg_x + (size_t)(rowA - B) * D);
    const int* idxB = (rowB < B) ? (pos_x + (size_t)rowB * D)
                                 : (neg_x + (size_t)(rowB - B) * D);
    const int4 a0 = *(const int4*)(idxA), a1 = *(const int4*)(idxA + 4);
    const int4 b0 = *(const int4*)(idxB), b1 = *(const int4*)(idxB + 4);
    const int idA[D] = {a0.x, a0.y, a0.z, a0.w, a1.x, a1.y, a1.z, a1.w};
    const int idB[D] = {b0.x, b0.y, b0.z, b0.w, b1.x, b1.y, b1.z, b1.w};

    // Issue all 16 dwordx4 gathers back-to-back (no intervening deps).
    float4 vA[D], vB[D];
#pragma unroll
    for (int d = 0; d < D; ++d)
        vA[d] = *(const float4*)(emb + (size_t)idA[d] * E + t * 4);
#pragma unroll
    for (int d = 0; d < D; ++d)
        vB[d] = *(const float4*)(emb + (size_t)idB[d] * E + t * 4);

    // Per-lane partials: p = sum_l s_l^2 - sum_l ss_l over this lane's 4 dims.
    float4 sA = make_float4(0.f, 0.f, 0.f, 0.f), qA = sA;
    float4 sB = sA, qB = sA;
#pragma unroll
    for (int d = 0; d < D; ++d) {
        sA.x += vA[d].x; sA.y += vA[d].y; sA.z += vA[d].z; sA.w += vA[d].w;
        qA.x += vA[d].x * vA[d].x; qA.y += vA[d].y * vA[d].y;
        qA.z += vA[d].z * vA[d].z; qA.w += vA[d].w * vA[d].w;
        sB.x += vB[d].x; sB.y += vB[d].y; sB.z += vB[d].z; sB.w += vB[d].w;
        qB.x += vB[d].x * vB[d].x; qB.y += vB[d].y * vB[d].y;
        qB.z += vB[d].z * vB[d].z; qB.w += vB[d].w * vB[d].w;
    }
    float pA = sA.x * sA.x + sA.y * sA.y + sA.z * sA.z + sA.w * sA.w
             - (qA.x + qA.y + qA.z + qA.w);
    float pB = sB.x * sB.x + sB.y * sB.y + sB.z * sB.z + sB.w * sB.w
             - (qB.x + qB.y + qB.z + qB.w);

    // Butterfly within each 16-lane group (xor 1,2,4,8).
#pragma unroll
    for (int off = 8; off > 0; off >>= 1) {
        pA += __shfl_xor(pA, off, 64);
        pB += __shfl_xor(pB, off, 64);
    }

    if (t == 0) {
        const float w  = expf(pair_w[0]);
        const float cc = c[0];
        out[rowA] = expf(0.5f * pA * w + cc);
        out[rowB] = expf(0.5f * pB * w + cc);
    }
}

extern "C" void kernel_launch(void* const* d_in, const int* in_sizes, int n_in,
                              void* d_out, int out_size, void* d_ws, size_t ws_size,
                              hipStream_t stream) {
    const int*   pos_x  = (const int*)  d_in[0];
    const int*   neg_x  = (const int*)  d_in[1];
    const float* emb    = (const float*)d_in[2];
    const float* pair_w = (const float*)d_in[3];
    const float* c      = (const float*)d_in[4];
    float*       out    = (float*)      d_out;

    constexpr int BLOCK = 256;                          // 4 waves/block
    constexpr int ROWS_PER_BLOCK = (BLOCK / 64) * RPW;  // 32
    static_assert(ROWS % ROWS_PER_BLOCK == 0, "exact grid");
    const int grid = ROWS / ROWS_PER_BLOCK;             // 5632

    APE_61555471286335_kernel<<<grid, BLOCK, 0, stream>>>(
        pos_x, neg_x, emb, pair_w, c, out);
}

// Round 5
// 211.018 us; speedup vs baseline: 1.0107x; 1.0107x over previous
//
#include <hip/hip_runtime.h>
#include <cstdint>

// Problem constants (from reference)
constexpr int B     = 16384;
constexpr int NNEG  = 10;
constexpr int D     = 8;
constexpr int E     = 64;               // 64 floats = 256B per table row
constexpr int ROWS  = B * (1 + NNEG);   // 180224; flat row id == output index
constexpr int RPW   = 4;                // output rows per wave (one per 16-lane group)
constexpr int WPB   = 4;                // waves per 256-thread block
constexpr int LDS_PER_WAVE = D * 1024;  // 8 DMA instrs x 1KB each

// pair_sum = sum_{i<j} e_i.e_j = 0.5*(||sum_d e_d||^2 - sum_d ||e_d||^2).
//
// Experiment: async direct-to-LDS gather. Lane l -> group g=l>>4 (output row),
// quad t=l&15 (dims [4t,4t+4)). One global_load_lds(size=16) = 64 lanes x 16B
// = 4 complete random table rows per instruction, deposited at
// lds_base + lane*16 (the HW-mandated wave-uniform-base + lane*size layout).
// Tests whether the DMA fill path tracks more outstanding line fills than the
// VGPR-return path (the round-3/4 Little's-law limiter).
__device__ __forceinline__ void dma16(const float* gp, void* lp) {
    __builtin_amdgcn_global_load_lds(
        (const __attribute__((address_space(1))) void*)gp,
        (__attribute__((address_space(3))) void*)lp,
        16, 0, 0);
}

__global__ __launch_bounds__(256) void APE_61555471286335_kernel(
    const int*   __restrict__ pos_x,   // [B, D]
    const int*   __restrict__ neg_x,   // [B, NNEG, D]
    const float* __restrict__ emb,     // [N_ENT, E]
    const float* __restrict__ pair_w,  // [N_PAIRS]
    const float* __restrict__ c,       // [1]
    float*       __restrict__ out)     // [ROWS]
{
    __shared__ char smem[WPB * LDS_PER_WAVE];   // 32 KB/block

    const int lane = threadIdx.x & 63;
    const int wid  = threadIdx.x >> 6;          // wave within block
    const int wave = blockIdx.x * WPB + wid;
    const int g    = lane >> 4;                 // output row within wave (0..3)
    const int t    = lane & 15;                 // quad: dims [4t, 4t+4)
    const int row  = wave * RPW + g;            // ROWS % 16 == 0, exact grid

    char* base = smem + wid * LDS_PER_WAVE;     // wave-uniform

    // 8 indices for this lane's row, two int4 loads (uniform per 16-lane group).
    const int* idx = (row < B) ? (pos_x + (size_t)row * D)
                               : (neg_x + (size_t)(row - B) * D);
    const int4 i0 = *(const int4*)(idx);
    const int4 i1 = *(const int4*)(idx + 4);
    const int id[D] = {i0.x, i0.y, i0.z, i0.w, i1.x, i1.y, i1.z, i1.w};

    // Issue 8 DMA gathers back-to-back. Instruction d deposits lane l's 16B at
    // base + d*1024 + l*16  ==  base + d*1024 + g*256 + t*16  (row g's quad t).
#pragma unroll
    for (int d = 0; d < D; ++d) {
        const float* gp = emb + (size_t)id[d] * E + t * 4;
        dma16(gp, base + d * 1024 + lane * 16);  // ptr arg wave-uniform in effect:
        // HW ignores per-lane offset beyond base+lane*16; base+d*1024 is uniform,
        // and lane*16 matches the HW deposit rule, so this spells the true dest.
    }

    // Drain DMA fills before reading LDS (syncthreads emits vmcnt(0) drain).
    __builtin_amdgcn_s_waitcnt(0x0f70);  // vmcnt(0) only
    __syncthreads();

    // Reduce: lane l reads back its own deposits (ds_read_b128, contiguous).
    float4 s = make_float4(0.f, 0.f, 0.f, 0.f), q = s;
#pragma unroll
    for (int d = 0; d < D; ++d) {
        const float4 v = *(const float4*)(base + d * 1024 + lane * 16);
        s.x += v.x; s.y += v.y; s.z += v.z; s.w += v.w;
        q.x += v.x * v.x; q.y += v.y * v.y;
        q.z += v.z * v.z; q.w += v.w * v.w;
    }
    float p = s.x * s.x + s.y * s.y + s.z * s.z + s.w * s.w
            - (q.x + q.y + q.z + q.w);

    // Butterfly within each 16-lane group.
#pragma unroll
    for (int off = 8; off > 0; off >>= 1)
        p += __shfl_xor(p, off, 64);

    if (t == 0) {
        out[row] = expf(0.5f * p * expf(pair_w[0]) + c[0]);
    }
}

extern "C" void kernel_launch(void* const* d_in, const int* in_sizes, int n_in,
                              void* d_out, int out_size, void* d_ws, size_t ws_size,
                              hipStream_t stream) {
    const int*   pos_x  = (const int*)  d_in[0];
    const int*   neg_x  = (const int*)  d_in[1];
    const float* emb    = (const float*)d_in[2];
    const float* pair_w = (const float*)d_in[3];
    const float* c      = (const float*)d_in[4];
    float*       out    = (float*)      d_out;

    constexpr int BLOCK = 256;
    constexpr int ROWS_PER_BLOCK = WPB * RPW;   // 16
    static_assert(ROWS % ROWS_PER_BLOCK == 0, "exact grid");
    const int grid = ROWS / ROWS_PER_BLOCK;     // 11264

    APE_61555471286335_kernel<<<grid, BLOCK, 0, stream>>>(
        pos_x, neg_x, emb, pair_w, c, out);
}